// Round 10
// baseline (899.093 us; speedup 1.0000x reference)
//
#include <hip/hip_runtime.h>
#include <hip/hip_bf16.h>
#include <stdint.h>

#define D_VIT 768
#define D_SAE 12288
#define NT64 192       // 64-feature tiles per row
#define TOPK 32
#define NC 48          // candidate superset target
#define CMAX 192
#define CHMAX 4096     // rows per chunk (L3 blocking)

typedef __attribute__((ext_vector_type(8))) short bf8_t;   // 8 bf16 (4 VGPRs)
typedef __attribute__((ext_vector_type(4))) float f4_t;    // 4 f32 acc
typedef const __attribute__((address_space(1))) void* gas_t;
typedef __attribute__((address_space(3))) void* las_t;

// ---------------- transpose W_enc (768 x 12288) -> wt f32 + wtb bf16 ---------
__global__ void k_transpose(const float* __restrict__ src, float* __restrict__ dst,
                            __hip_bfloat16* __restrict__ dstb) {
    __shared__ float t[32][33];
    int f0 = blockIdx.x * 32, k0 = blockIdx.y * 32;
    int tx = threadIdx.x, ty = threadIdx.y;
#pragma unroll
    for (int j = 0; j < 32; j += 8)
        t[ty + j][tx] = src[(size_t)(k0 + ty + j) * D_SAE + f0 + tx];
    __syncthreads();
#pragma unroll
    for (int j = 0; j < 32; j += 8) {
        float v = t[tx][ty + j];
        dst[(size_t)(f0 + ty + j) * D_VIT + k0 + tx] = v;
        dstb[(size_t)(f0 + ty + j) * D_VIT + k0 + tx] = __float2bfloat16(v);
    }
}

// ---------------- xb = bf16(x - b_dec) ---------------------------------------
__global__ __launch_bounds__(256) void k_cvt_x(const float* __restrict__ x,
    const float* __restrict__ bdec, __hip_bfloat16* __restrict__ xb, long long n) {
    long long i = ((long long)blockIdx.x * 256 + threadIdx.x) * 8;
    if (i >= n) return;
    float4 a = *reinterpret_cast<const float4*>(x + i);
    float4 b = *reinterpret_cast<const float4*>(x + i + 4);
    int kk = (int)(i % D_VIT);
    float4 c = *reinterpret_cast<const float4*>(bdec + kk);
    float4 d = *reinterpret_cast<const float4*>(bdec + kk + 4);
    union { __hip_bfloat16 h[8]; uint4 v; } o;
    o.h[0] = __float2bfloat16(a.x - c.x); o.h[1] = __float2bfloat16(a.y - c.y);
    o.h[2] = __float2bfloat16(a.z - c.z); o.h[3] = __float2bfloat16(a.w - c.w);
    o.h[4] = __float2bfloat16(b.x - d.x); o.h[5] = __float2bfloat16(b.y - d.y);
    o.h[6] = __float2bfloat16(b.z - d.z); o.h[7] = __float2bfloat16(b.w - d.w);
    *reinterpret_cast<uint4*>(xb + i) = o.v;
}

// ---------------- wdecb = bf16(wdec) -----------------------------------------
__global__ __launch_bounds__(256) void k_cvt_w(const float* __restrict__ wdec,
    __hip_bfloat16* __restrict__ wdecb, long long n) {
    long long i = ((long long)blockIdx.x * 256 + threadIdx.x) * 8;
    if (i >= n) return;
    float4 a = *reinterpret_cast<const float4*>(wdec + i);
    float4 b = *reinterpret_cast<const float4*>(wdec + i + 4);
    union { __hip_bfloat16 h[8]; uint4 v; } o;
    o.h[0] = __float2bfloat16(a.x); o.h[1] = __float2bfloat16(a.y);
    o.h[2] = __float2bfloat16(a.z); o.h[3] = __float2bfloat16(a.w);
    o.h[4] = __float2bfloat16(b.x); o.h[5] = __float2bfloat16(b.y);
    o.h[6] = __float2bfloat16(b.z); o.h[7] = __float2bfloat16(b.w);
    *reinterpret_cast<uint4*>(wdecb + i) = o.v;
}

// ------- 256x256x64 8-wave double-buffered MFMA encoder + tile-max out -------
#define GBM 256
#define GBN 256
#define GBK 64
#define NKT (D_VIT / GBK)   // 12

__global__ __launch_bounds__(512, 2) void k_enc8(
    const __hip_bfloat16* __restrict__ xb, const __hip_bfloat16* __restrict__ wtb,
    __hip_bfloat16* __restrict__ actsb, __hip_bfloat16* __restrict__ maxv,
    int row0, int mrows, int Mtot) {
    __shared__ __hip_bfloat16 lds[2][2][GBM * GBK];   // 128 KiB
    int tid = threadIdx.x;
    int lane = tid & 63, w = tid >> 6;
    int wm = w >> 2, wn = w & 3;                      // 2 x 4 waves
    int tile_m = blockIdx.y * GBM, tile_n = blockIdx.x * GBN;
    int lrow = lane & 15, lk = lane >> 4;
    int G0 = w * 64 + lane;

    f4_t acc[2][4][2][2] = {};                        // [mq][f][nq][g]

    auto STAGE = [&](int kt, int h, int b) {
#pragma unroll
        for (int j = 0; j < 2; ++j) {
            int G = G0 + j * 512;
            int r = G >> 3, s = G & 7;
            int gg = s ^ (r & 7);
            int half = h >> 1;
            if ((h & 1) == 0) {
                int ar = row0 + tile_m + half * 128 + r;
                if (ar >= Mtot) ar = Mtot - 1;
                const __hip_bfloat16* src = xb + (size_t)ar * D_VIT + kt * GBK + gg * 8;
                __builtin_amdgcn_global_load_lds((gas_t)src,
                    (las_t)(&lds[b][0][half * 8192 + (w * 64 + j * 512) * 8]), 16, 0, 0);
            } else {
                int br = tile_n + half * 128 + r;
                const __hip_bfloat16* src = wtb + (size_t)br * D_VIT + kt * GBK + gg * 8;
                __builtin_amdgcn_global_load_lds((gas_t)src,
                    (las_t)(&lds[b][1][half * 8192 + (w * 64 + j * 512) * 8]), 16, 0, 0);
            }
        }
    };

#define PHASE(MQ, NQ, BUF) do {                                                \
        const __hip_bfloat16* Ab = &lds[BUF][0][0];                            \
        const __hip_bfloat16* Bb = &lds[BUF][1][0];                            \
        bf8_t af[4][2], bv[2][2];                                              \
        _Pragma("unroll")                                                      \
        for (int f = 0; f < 4; ++f) {                                          \
            int ra = wm * 128 + (MQ) * 64 + f * 16 + lrow;                     \
            _Pragma("unroll")                                                  \
            for (int h = 0; h < 2; ++h) {                                      \
                int sl = (lk + 4 * h) ^ (ra & 7);                              \
                af[f][h] = *reinterpret_cast<const bf8_t*>(Ab + ra * GBK + sl * 8); \
            }                                                                  \
        }                                                                      \
        _Pragma("unroll")                                                      \
        for (int g = 0; g < 2; ++g) {                                          \
            int rb = wn * 64 + (NQ) * 32 + g * 16 + lrow;                      \
            _Pragma("unroll")                                                  \
            for (int h = 0; h < 2; ++h) {                                      \
                int sl = (lk + 4 * h) ^ (rb & 7);                              \
                bv[g][h] = *reinterpret_cast<const bf8_t*>(Bb + rb * GBK + sl * 8); \
            }                                                                  \
        }                                                                      \
        __builtin_amdgcn_s_setprio(1);                                         \
        _Pragma("unroll")                                                      \
        for (int h = 0; h < 2; ++h)                                            \
            _Pragma("unroll")                                                  \
            for (int f = 0; f < 4; ++f)                                        \
                _Pragma("unroll")                                              \
                for (int g = 0; g < 2; ++g)                                    \
                    acc[MQ][f][NQ][g] = __builtin_amdgcn_mfma_f32_16x16x32_bf16( \
                        bv[g][h], af[f][h], acc[MQ][f][NQ][g], 0, 0, 0);       \
        __builtin_amdgcn_s_setprio(0);                                         \
    } while (0)

#pragma unroll
    for (int h = 0; h < 4; ++h) STAGE(0, h, 0);

    int cur = 0;
#pragma unroll 1
    for (int t = 0; t < NKT; ++t) {
        int nb = cur ^ 1;
        bool pf = (t + 1 < NKT);
        if (pf) STAGE(t + 1, 0, nb);
        if (pf) asm volatile("s_waitcnt vmcnt(2)" ::: "memory");
        else    asm volatile("s_waitcnt vmcnt(0)" ::: "memory");
        __builtin_amdgcn_s_barrier();
        asm volatile("" ::: "memory");
        __builtin_amdgcn_sched_barrier(0);
        PHASE(0, 0, cur);
        if (pf) STAGE(t + 1, 1, nb);
        PHASE(1, 0, cur);
        if (pf) STAGE(t + 1, 2, nb);
        PHASE(0, 1, cur);
        if (pf) STAGE(t + 1, 3, nb);
        PHASE(1, 1, cur);
        asm volatile("" ::: "memory");
        __builtin_amdgcn_s_barrier();
        asm volatile("" ::: "memory");
        cur = nb;
    }
#undef PHASE

    // C-write + per-64-feature-tile max (bf16 round is monotone: round(max f32)
    // == max(stored bf16), so maxv is exactly the max of stored codes)
    int tn64 = blockIdx.x * 4 + wn;    // this wave's 64-feature tile index
#pragma unroll
    for (int mq = 0; mq < 2; ++mq)
#pragma unroll
        for (int f = 0; f < 4; ++f) {
            int xr = tile_m + wm * 128 + mq * 64 + f * 16 + lrow;
            float mx = 0.f;
            if (xr < mrows) {
                __hip_bfloat16* rowp = actsb + (size_t)xr * D_SAE;
#pragma unroll
                for (int nq = 0; nq < 2; ++nq)
#pragma unroll
                    for (int g = 0; g < 2; ++g) {
                        int fb = tile_n + wn * 64 + nq * 32 + g * 16 + lk * 4;
                        union { __hip_bfloat16 h4[4]; uint2 u; } o;
                        float r0 = fmaxf(acc[mq][f][nq][g][0], 0.f);
                        float r1 = fmaxf(acc[mq][f][nq][g][1], 0.f);
                        float r2 = fmaxf(acc[mq][f][nq][g][2], 0.f);
                        float r3 = fmaxf(acc[mq][f][nq][g][3], 0.f);
                        mx = fmaxf(mx, fmaxf(fmaxf(r0, r1), fmaxf(r2, r3)));
                        o.h4[0] = __float2bfloat16(r0);
                        o.h4[1] = __float2bfloat16(r1);
                        o.h4[2] = __float2bfloat16(r2);
                        o.h4[3] = __float2bfloat16(r3);
                        *reinterpret_cast<uint2*>(rowp + fb) = o.u;
                    }
            }
            mx = fmaxf(mx, __shfl_xor(mx, 16));
            mx = fmaxf(mx, __shfl_xor(mx, 32));
            if (lk == 0 && xr < mrows)
                maxv[(size_t)xr * NT64 + tn64] = __float2bfloat16(mx);
        }
}

// -------- per-row: tile-max prescreen -> band-limited f64 rerank -> decode ---
__global__ __launch_bounds__(256) void k_select(
    const __hip_bfloat16* __restrict__ actsb, const unsigned short* __restrict__ maxv,
    const float* __restrict__ x, const float* __restrict__ bdec,
    const float* __restrict__ wt, const __hip_bfloat16* __restrict__ wdecb,
    float* __restrict__ out, int row0, int mrows) {
    int lrow = blockIdx.x;
    int row = row0 + lrow;
    int tid = threadIdx.x;

    __shared__ float xs[D_VIT];
    __shared__ unsigned short tmax[NT64];
    __shared__ short stile[NT64];
    __shared__ int cand[CMAX];
    __shared__ float cvfin[CMAX];
    __shared__ float cexact[CMAX];
    __shared__ unsigned char cflag[CMAX];
    __shared__ int alist[CMAX];
    __shared__ float sval[TOPK];
    __shared__ int sidx[TOPK];
    __shared__ int s_cnt, s_ns, s_na, s_nd;
    __shared__ unsigned int s_tau;
    __shared__ float s_vb;

    if (tid < CMAX) cflag[tid] = 0;
    if (tid < TOPK) { sval[tid] = 0.f; sidx[tid] = 0; }
    if (tid == 0) { s_cnt = 0; s_ns = 0; s_na = 0; s_nd = 0; s_tau = 0; s_vb = 0.f; }
    for (int i = tid; i < D_VIT; i += 256)
        xs[i] = x[(size_t)row * D_VIT + i] - bdec[i];
    if (tid < NT64) tmax[tid] = maxv[(size_t)lrow * NT64 + tid];
    __syncthreads();

    // tau = NC-th largest tile-max code (index tiebreak). Guarantee: >= NC
    // values have code >= tau, and every value with code >= tau lies in a
    // surviving tile -> candidate set == {all values with code >= tau}.
    if (tid < NT64) {
        unsigned mc = tmax[tid];
        int rank = 0;
        for (int j = 0; j < NT64; ++j) {
            unsigned cj = tmax[j];
            rank += (cj > mc) || (cj == mc && j < tid);
        }
        if (rank == NC - 1) s_tau = mc;
    }
    __syncthreads();
    unsigned tau = s_tau; if (tau == 0) tau = 1;
    if (tid < NT64 && (unsigned)tmax[tid] >= tau) {
        int sl = atomicAdd(&s_ns, 1);
        stile[sl] = (short)tid;
    }
    __syncthreads();
    int ns = s_ns;

    // collect candidates from surviving tiles (64 threads per tile)
    const unsigned short* actsu = reinterpret_cast<const unsigned short*>(
        actsb + (size_t)lrow * D_SAE);
    for (int i = tid >> 6; i < ns; i += 4) {
        int t = stile[i];
        int fidx = t * 64 + (tid & 63);
        unsigned code = actsu[fidx];
        if (code >= tau && code < 0x8000u) {
            int slot = atomicAdd(&s_cnt, 1);
            if (slot < CMAX) cand[slot] = (int)((code << 16) | (unsigned)fidx);
        }
    }
    __syncthreads();
    int C = s_cnt < CMAX ? s_cnt : CMAX;

    // code-rank; vb = 32nd largest bf16 value
    int myidx = 0; float myval = 0.f;
    if (tid < C) {
        unsigned mypack = (unsigned)cand[tid];
        unsigned mycode = mypack >> 16; myidx = (int)(mypack & 0xffffu);
        myval = __uint_as_float(mycode << 16);
        int myrank = 0;
        for (int j = 0; j < C; ++j) {
            unsigned pj = (unsigned)cand[j];
            unsigned cj = pj >> 16; int ij = (int)(pj & 0xffffu);
            myrank += (cj > mycode) || (cj == mycode && ij < myidx);
        }
        if (C > 32 && myrank == 31) s_vb = myval;
    }
    __syncthreads();

    // partition: definite-in / ambiguous band / excluded
    if (tid < C) {
        if (C <= 32) { cflag[tid] = 2; cvfin[tid] = myval; }
        else {
            float vb = s_vb;
            float band = 0.025f + 0.018f * vb;
            if (myval > vb + band) { cflag[tid] = 2; cvfin[tid] = myval; atomicAdd(&s_nd, 1); }
            else if (myval >= vb - band) { int a = atomicAdd(&s_na, 1); alist[a] = tid; cflag[tid] = 1; }
        }
    }
    __syncthreads();
    int na = s_na, nd = s_nd;

    // f64 rerank of band only: 8 cands x 32 threads
    for (int base = 0; base < na; base += 8) {
        int ai = base + (tid >> 5), sub = tid & 31;
        if (ai < na) {
            int c = alist[ai];
            int f = (int)(((unsigned)cand[c]) & 0xffffu);
            const float* wr = wt + (size_t)f * D_VIT;
            double acc = 0.0;
            for (int k = sub * 4; k < D_VIT; k += 128) {
                float4 wv = *reinterpret_cast<const float4*>(wr + k);
                float4 xv = *reinterpret_cast<const float4*>(xs + k);
                acc += (double)wv.x * xv.x + (double)wv.y * xv.y
                     + (double)wv.z * xv.z + (double)wv.w * xv.w;
            }
            acc += __shfl_xor(acc, 1);  acc += __shfl_xor(acc, 2);
            acc += __shfl_xor(acc, 4);  acc += __shfl_xor(acc, 8);
            acc += __shfl_xor(acc, 16);
            if (sub == 0) cexact[c] = (float)(acc > 0.0 ? acc : 0.0);
        }
    }
    __syncthreads();

    // choose top (32-nd) of the band by exact value
    if (C > 32 && tid < C && cflag[tid] == 1) {
        int kq = TOPK - nd;
        float ex = cexact[tid]; int rankA = 0;
        for (int j = 0; j < na; ++j) {
            int cj = alist[j];
            float ej = cexact[cj]; int ij = (int)(((unsigned)cand[cj]) & 0xffffu);
            rankA += (ej > ex) || (ej == ex && ij < myidx);
        }
        if (rankA < kq) { cflag[tid] = 3; cvfin[tid] = ex; }
    }
    __syncthreads();

    // deterministic slot routing among the chosen
    if (tid < C && cflag[tid] >= 2) {
        float mv = cvfin[tid]; int rank = 0;
        for (int j = 0; j < C; ++j) {
            if (cflag[j] >= 2) {
                float vj = cvfin[j]; int ij = (int)(((unsigned)cand[j]) & 0xffffu);
                rank += (vj > mv) || (vj == mv && ij < myidx);
            }
        }
        if (rank < TOPK) { sval[rank] = mv; sidx[rank] = myidx; }
    }
    __syncthreads();

    // sparse decode from bf16 wdec + b_dec; nt store
    for (int d = tid; d < D_VIT; d += 256) {
        float o = bdec[d];
#pragma unroll
        for (int j = 0; j < TOPK; j++)
            o = fmaf(sval[j], __bfloat162float(wdecb[(size_t)sidx[j] * D_VIT + d]), o);
        __builtin_nontemporal_store(o, out + (size_t)row * D_VIT + d);
    }
}

extern "C" void kernel_launch(void* const* d_in, const int* in_sizes, int n_in,
                              void* d_out, int out_size, void* d_ws, size_t ws_size,
                              hipStream_t stream) {
    const float* x    = (const float*)d_in[0];
    const float* wenc = (const float*)d_in[1];
    const float* wdec = (const float*)d_in[2];
    const float* bdec = (const float*)d_in[3];
    float* out = (float*)d_out;
    int M = in_sizes[0] / D_VIT;

    size_t wt_b    = (size_t)D_SAE * D_VIT * sizeof(float);
    size_t wtb_b   = (size_t)D_SAE * D_VIT * sizeof(__hip_bfloat16);
    size_t xb_b    = (size_t)M * D_VIT * sizeof(__hip_bfloat16);
    size_t wdecb_b = (size_t)D_SAE * D_VIT * sizeof(__hip_bfloat16);
    size_t fixed   = wt_b + wtb_b + xb_b + wdecb_b;
    size_t row_b   = (size_t)D_SAE * sizeof(__hip_bfloat16) + NT64 * sizeof(__hip_bfloat16);

    float* wt             = (float*)d_ws;
    __hip_bfloat16* wtb   = (__hip_bfloat16*)((char*)d_ws + wt_b);
    __hip_bfloat16* xb    = (__hip_bfloat16*)((char*)d_ws + wt_b + wtb_b);
    __hip_bfloat16* wdecb = (__hip_bfloat16*)((char*)d_ws + wt_b + wtb_b + xb_b);

    long long chl = (long long)((ws_size > fixed ? ws_size - fixed : row_b) / row_b);
    int CH = (int)(chl < 1 ? 1 : (chl > (long long)M ? M : chl));
    if (CH > CHMAX) CH = CHMAX;
    if (CH >= 256 && CH < M) CH &= ~255;

    __hip_bfloat16* mx_buf = (__hip_bfloat16*)((char*)d_ws + fixed);
    __hip_bfloat16* actb   = (__hip_bfloat16*)((char*)d_ws + fixed
                                               + (size_t)CH * NT64 * sizeof(__hip_bfloat16));

    {
        dim3 g(D_SAE / 32, D_VIT / 32), b(32, 8);
        hipLaunchKernelGGL(k_transpose, g, b, 0, stream, wenc, wt, wtb);
    }
    {
        long long n = (long long)M * D_VIT;
        int blocks = (int)((n / 8 + 255) / 256);
        hipLaunchKernelGGL(k_cvt_x, dim3(blocks), dim3(256), 0, stream, x, bdec, xb, n);
    }
    {
        long long n = (long long)D_SAE * D_VIT;
        int blocks = (int)((n / 8 + 255) / 256);
        hipLaunchKernelGGL(k_cvt_w, dim3(blocks), dim3(256), 0, stream, wdec, wdecb, n);
    }
    for (int s = 0; s < M; s += CH) {
        int mr = (M - s) < CH ? (M - s) : CH;
        dim3 ge(D_SAE / GBN, (mr + GBM - 1) / GBM), be(512);
        hipLaunchKernelGGL(k_enc8, ge, be, 0, stream, xb, wtb, actb, mx_buf, s, mr, M);
        hipLaunchKernelGGL(k_select, dim3(mr), dim3(256), 0, stream,
                           actb, (const unsigned short*)mx_buf, x, bdec, wt, wdecb,
                           out, s, mr);
    }
}

// Round 11
// 879.059 us; speedup vs baseline: 1.0228x; 1.0228x over previous
//
#include <hip/hip_runtime.h>
#include <hip/hip_bf16.h>
#include <stdint.h>

#define D_VIT 768
#define D_SAE 12288
#define NT64 192       // 64-feature tiles per row
#define TOPK 32
#define NC 48          // candidate superset target
#define CMAX 192
#define CHMAX 4096     // rows per chunk

typedef __attribute__((ext_vector_type(8))) short bf8_t;   // 8 bf16 (4 VGPRs)
typedef __attribute__((ext_vector_type(4))) float f4_t;    // 4 f32 acc
typedef const __attribute__((address_space(1))) void* gas_t;
typedef __attribute__((address_space(3))) void* las_t;

// ---------------- transpose W_enc (768 x 12288) -> wt f32 + wtb bf16 ---------
__global__ void k_transpose(const float* __restrict__ src, float* __restrict__ dst,
                            __hip_bfloat16* __restrict__ dstb) {
    __shared__ float t[32][33];
    int f0 = blockIdx.x * 32, k0 = blockIdx.y * 32;
    int tx = threadIdx.x, ty = threadIdx.y;
#pragma unroll
    for (int j = 0; j < 32; j += 8)
        t[ty + j][tx] = src[(size_t)(k0 + ty + j) * D_SAE + f0 + tx];
    __syncthreads();
#pragma unroll
    for (int j = 0; j < 32; j += 8) {
        float v = t[tx][ty + j];
        dst[(size_t)(f0 + ty + j) * D_VIT + k0 + tx] = v;
        dstb[(size_t)(f0 + ty + j) * D_VIT + k0 + tx] = __float2bfloat16(v);
    }
}

// ---------------- xb = bf16(x - b_dec) ---------------------------------------
__global__ __launch_bounds__(256) void k_cvt_x(const float* __restrict__ x,
    const float* __restrict__ bdec, __hip_bfloat16* __restrict__ xb, long long n) {
    long long i = ((long long)blockIdx.x * 256 + threadIdx.x) * 8;
    if (i >= n) return;
    float4 a = *reinterpret_cast<const float4*>(x + i);
    float4 b = *reinterpret_cast<const float4*>(x + i + 4);
    int kk = (int)(i % D_VIT);
    float4 c = *reinterpret_cast<const float4*>(bdec + kk);
    float4 d = *reinterpret_cast<const float4*>(bdec + kk + 4);
    union { __hip_bfloat16 h[8]; uint4 v; } o;
    o.h[0] = __float2bfloat16(a.x - c.x); o.h[1] = __float2bfloat16(a.y - c.y);
    o.h[2] = __float2bfloat16(a.z - c.z); o.h[3] = __float2bfloat16(a.w - c.w);
    o.h[4] = __float2bfloat16(b.x - d.x); o.h[5] = __float2bfloat16(b.y - d.y);
    o.h[6] = __float2bfloat16(b.z - d.z); o.h[7] = __float2bfloat16(b.w - d.w);
    *reinterpret_cast<uint4*>(xb + i) = o.v;
}

// ---------------- wdecb = bf16(wdec) -----------------------------------------
__global__ __launch_bounds__(256) void k_cvt_w(const float* __restrict__ wdec,
    __hip_bfloat16* __restrict__ wdecb, long long n) {
    long long i = ((long long)blockIdx.x * 256 + threadIdx.x) * 8;
    if (i >= n) return;
    float4 a = *reinterpret_cast<const float4*>(wdec + i);
    float4 b = *reinterpret_cast<const float4*>(wdec + i + 4);
    union { __hip_bfloat16 h[8]; uint4 v; } o;
    o.h[0] = __float2bfloat16(a.x); o.h[1] = __float2bfloat16(a.y);
    o.h[2] = __float2bfloat16(a.z); o.h[3] = __float2bfloat16(a.w);
    o.h[4] = __float2bfloat16(b.x); o.h[5] = __float2bfloat16(b.y);
    o.h[6] = __float2bfloat16(b.z); o.h[7] = __float2bfloat16(b.w);
    *reinterpret_cast<uint4*>(wdecb + i) = o.v;
}

// ------- 256x256x64 8-wave double-buffered MFMA encoder + tile-max out -------
#define GBM 256
#define GBN 256
#define GBK 64
#define NKT (D_VIT / GBK)   // 12

__global__ __launch_bounds__(512, 2) void k_enc8(
    const __hip_bfloat16* __restrict__ xb, const __hip_bfloat16* __restrict__ wtb,
    __hip_bfloat16* __restrict__ actsb, __hip_bfloat16* __restrict__ maxv,
    int row0, int mrows, int Mtot) {
    __shared__ __hip_bfloat16 lds[2][2][GBM * GBK];   // 128 KiB
    int tid = threadIdx.x;
    int lane = tid & 63, w = tid >> 6;
    int wm = w >> 2, wn = w & 3;                      // 2 x 4 waves
    int tile_m = blockIdx.y * GBM, tile_n = blockIdx.x * GBN;
    int lrow = lane & 15, lk = lane >> 4;
    int G0 = w * 64 + lane;

    f4_t acc[2][4][2][2] = {};                        // [mq][f][nq][g]

    auto STAGE = [&](int kt, int h, int b) {
#pragma unroll
        for (int j = 0; j < 2; ++j) {
            int G = G0 + j * 512;
            int r = G >> 3, s = G & 7;
            int gg = s ^ (r & 7);
            int half = h >> 1;
            if ((h & 1) == 0) {
                int ar = row0 + tile_m + half * 128 + r;
                if (ar >= Mtot) ar = Mtot - 1;
                const __hip_bfloat16* src = xb + (size_t)ar * D_VIT + kt * GBK + gg * 8;
                __builtin_amdgcn_global_load_lds((gas_t)src,
                    (las_t)(&lds[b][0][half * 8192 + (w * 64 + j * 512) * 8]), 16, 0, 0);
            } else {
                int br = tile_n + half * 128 + r;
                const __hip_bfloat16* src = wtb + (size_t)br * D_VIT + kt * GBK + gg * 8;
                __builtin_amdgcn_global_load_lds((gas_t)src,
                    (las_t)(&lds[b][1][half * 8192 + (w * 64 + j * 512) * 8]), 16, 0, 0);
            }
        }
    };

#define PHASE(MQ, NQ, BUF) do {                                                \
        const __hip_bfloat16* Ab = &lds[BUF][0][0];                            \
        const __hip_bfloat16* Bb = &lds[BUF][1][0];                            \
        bf8_t af[4][2], bv[2][2];                                              \
        _Pragma("unroll")                                                      \
        for (int f = 0; f < 4; ++f) {                                          \
            int ra = wm * 128 + (MQ) * 64 + f * 16 + lrow;                     \
            _Pragma("unroll")                                                  \
            for (int h = 0; h < 2; ++h) {                                      \
                int sl = (lk + 4 * h) ^ (ra & 7);                              \
                af[f][h] = *reinterpret_cast<const bf8_t*>(Ab + ra * GBK + sl * 8); \
            }                                                                  \
        }                                                                      \
        _Pragma("unroll")                                                      \
        for (int g = 0; g < 2; ++g) {                                          \
            int rb = wn * 64 + (NQ) * 32 + g * 16 + lrow;                      \
            _Pragma("unroll")                                                  \
            for (int h = 0; h < 2; ++h) {                                      \
                int sl = (lk + 4 * h) ^ (rb & 7);                              \
                bv[g][h] = *reinterpret_cast<const bf8_t*>(Bb + rb * GBK + sl * 8); \
            }                                                                  \
        }                                                                      \
        __builtin_amdgcn_s_setprio(1);                                         \
        _Pragma("unroll")                                                      \
        for (int h = 0; h < 2; ++h)                                            \
            _Pragma("unroll")                                                  \
            for (int f = 0; f < 4; ++f)                                        \
                _Pragma("unroll")                                              \
                for (int g = 0; g < 2; ++g)                                    \
                    acc[MQ][f][NQ][g] = __builtin_amdgcn_mfma_f32_16x16x32_bf16( \
                        bv[g][h], af[f][h], acc[MQ][f][NQ][g], 0, 0, 0);       \
        __builtin_amdgcn_s_setprio(0);                                         \
    } while (0)

#pragma unroll
    for (int h = 0; h < 4; ++h) STAGE(0, h, 0);

    int cur = 0;
#pragma unroll 1
    for (int t = 0; t < NKT; ++t) {
        int nb = cur ^ 1;
        bool pf = (t + 1 < NKT);
        if (pf) STAGE(t + 1, 0, nb);
        if (pf) asm volatile("s_waitcnt vmcnt(2)" ::: "memory");
        else    asm volatile("s_waitcnt vmcnt(0)" ::: "memory");
        __builtin_amdgcn_s_barrier();
        asm volatile("" ::: "memory");
        __builtin_amdgcn_sched_barrier(0);
        PHASE(0, 0, cur);
        if (pf) STAGE(t + 1, 1, nb);
        PHASE(1, 0, cur);
        if (pf) STAGE(t + 1, 2, nb);
        PHASE(0, 1, cur);
        if (pf) STAGE(t + 1, 3, nb);
        PHASE(1, 1, cur);
        asm volatile("" ::: "memory");
        __builtin_amdgcn_s_barrier();
        asm volatile("" ::: "memory");
        cur = nb;
    }
#undef PHASE

    // C-write + per-64-feature-tile max (bf16 round monotone -> maxv is exact
    // max of stored codes)
    int tn64 = blockIdx.x * 4 + wn;
#pragma unroll
    for (int mq = 0; mq < 2; ++mq)
#pragma unroll
        for (int f = 0; f < 4; ++f) {
            int xr = tile_m + wm * 128 + mq * 64 + f * 16 + lrow;
            float mx = 0.f;
            if (xr < mrows) {
                __hip_bfloat16* rowp = actsb + (size_t)xr * D_SAE;
#pragma unroll
                for (int nq = 0; nq < 2; ++nq)
#pragma unroll
                    for (int g = 0; g < 2; ++g) {
                        int fb = tile_n + wn * 64 + nq * 32 + g * 16 + lk * 4;
                        union { __hip_bfloat16 h4[4]; uint2 u; } o;
                        float r0 = fmaxf(acc[mq][f][nq][g][0], 0.f);
                        float r1 = fmaxf(acc[mq][f][nq][g][1], 0.f);
                        float r2 = fmaxf(acc[mq][f][nq][g][2], 0.f);
                        float r3 = fmaxf(acc[mq][f][nq][g][3], 0.f);
                        mx = fmaxf(mx, fmaxf(fmaxf(r0, r1), fmaxf(r2, r3)));
                        o.h4[0] = __float2bfloat16(r0);
                        o.h4[1] = __float2bfloat16(r1);
                        o.h4[2] = __float2bfloat16(r2);
                        o.h4[3] = __float2bfloat16(r3);
                        *reinterpret_cast<uint2*>(rowp + fb) = o.u;
                    }
            }
            mx = fmaxf(mx, __shfl_xor(mx, 16));
            mx = fmaxf(mx, __shfl_xor(mx, 32));
            if (lk == 0 && xr < mrows)
                maxv[(size_t)xr * NT64 + tn64] = __float2bfloat16(mx);
        }
}

// -------- per-row: tile-max prescreen -> band-limited f64 rerank -> decode ---
__global__ __launch_bounds__(256) void k_select(
    const __hip_bfloat16* __restrict__ actsb, const unsigned short* __restrict__ maxv,
    const float* __restrict__ x, const float* __restrict__ bdec,
    const float* __restrict__ wt, const __hip_bfloat16* __restrict__ wdecb,
    float* __restrict__ out, int row0, int mrows) {
    int lrow = blockIdx.x;
    int row = row0 + lrow;
    int tid = threadIdx.x;

    __shared__ float xs[D_VIT];
    __shared__ unsigned short tmax[NT64];
    __shared__ short stile[NT64];
    __shared__ int cand[CMAX];
    __shared__ float cvfin[CMAX];
    __shared__ float cexact[CMAX];
    __shared__ unsigned char cflag[CMAX];
    __shared__ int alist[CMAX];
    __shared__ float sval[TOPK];
    __shared__ int sidx[TOPK];
    __shared__ int s_cnt, s_ns, s_na, s_nd;
    __shared__ unsigned int s_tau;
    __shared__ float s_vb;

    if (tid < CMAX) cflag[tid] = 0;
    if (tid < TOPK) { sval[tid] = 0.f; sidx[tid] = 0; }
    if (tid == 0) { s_cnt = 0; s_ns = 0; s_na = 0; s_nd = 0; s_tau = 0; s_vb = 0.f; }
    for (int i = tid; i < D_VIT; i += 256)
        xs[i] = x[(size_t)row * D_VIT + i] - bdec[i];
    if (tid < NT64) tmax[tid] = maxv[(size_t)lrow * NT64 + tid];
    __syncthreads();

    // tau = NC-th largest tile-max code (index tiebreak); candidate set ==
    // {all values with code >= tau} (provably a superset of code-top-NC).
    if (tid < NT64) {
        unsigned mc = tmax[tid];
        int rank = 0;
        for (int j = 0; j < NT64; ++j) {
            unsigned cj = tmax[j];
            rank += (cj > mc) || (cj == mc && j < tid);
        }
        if (rank == NC - 1) s_tau = mc;
    }
    __syncthreads();
    unsigned tau = s_tau; if (tau == 0) tau = 1;
    if (tid < NT64 && (unsigned)tmax[tid] >= tau) {
        int sl = atomicAdd(&s_ns, 1);
        stile[sl] = (short)tid;
    }
    __syncthreads();
    int ns = s_ns;

    // register-staged two-phase gather (MLP: all loads issue before any atomic)
    const unsigned short* actsu = reinterpret_cast<const unsigned short*>(
        actsb + (size_t)lrow * D_SAE);
    int tot = ns * 64;
    for (int base = 0; base < tot; base += 4096) {
        unsigned codes[16];
        int fidxs[16];
#pragma unroll
        for (int i = 0; i < 16; ++i) {
            int e = base + tid + 256 * i;
            int valid = e < tot;
            int t = (int)stile[valid ? (e >> 6) : 0];
            int fidx = t * 64 + (e & 63);
            fidxs[i] = fidx;
            codes[i] = valid ? (unsigned)actsu[fidx] : 0u;
        }
#pragma unroll
        for (int i = 0; i < 16; ++i) {
            int e = base + tid + 256 * i;
            unsigned code = codes[i];
            if (e < tot && code >= tau && code < 0x8000u) {
                int slot = atomicAdd(&s_cnt, 1);
                if (slot < CMAX) cand[slot] = (int)((code << 16) | (unsigned)fidxs[i]);
            }
        }
    }
    __syncthreads();
    int C = s_cnt < CMAX ? s_cnt : CMAX;

    // code-rank; vb = 32nd largest bf16 value
    int myidx = 0; float myval = 0.f;
    if (tid < C) {
        unsigned mypack = (unsigned)cand[tid];
        unsigned mycode = mypack >> 16; myidx = (int)(mypack & 0xffffu);
        myval = __uint_as_float(mycode << 16);
        int myrank = 0;
        for (int j = 0; j < C; ++j) {
            unsigned pj = (unsigned)cand[j];
            unsigned cj = pj >> 16; int ij = (int)(pj & 0xffffu);
            myrank += (cj > mycode) || (cj == mycode && ij < myidx);
        }
        if (C > 32 && myrank == 31) s_vb = myval;
    }
    __syncthreads();

    // partition: definite-in / ambiguous band / excluded
    if (tid < C) {
        if (C <= 32) { cflag[tid] = 2; cvfin[tid] = myval; }
        else {
            float vb = s_vb;
            float band = 0.025f + 0.018f * vb;
            if (myval > vb + band) { cflag[tid] = 2; cvfin[tid] = myval; atomicAdd(&s_nd, 1); }
            else if (myval >= vb - band) { int a = atomicAdd(&s_na, 1); alist[a] = tid; cflag[tid] = 1; }
        }
    }
    __syncthreads();
    int na = s_na, nd = s_nd;

    // f64 rerank of band only: 8 cands x 32 threads
    for (int base = 0; base < na; base += 8) {
        int ai = base + (tid >> 5), sub = tid & 31;
        if (ai < na) {
            int c = alist[ai];
            int f = (int)(((unsigned)cand[c]) & 0xffffu);
            const float* wr = wt + (size_t)f * D_VIT;
            double acc = 0.0;
            for (int k = sub * 4; k < D_VIT; k += 128) {
                float4 wv = *reinterpret_cast<const float4*>(wr + k);
                float4 xv = *reinterpret_cast<const float4*>(xs + k);
                acc += (double)wv.x * xv.x + (double)wv.y * xv.y
                     + (double)wv.z * xv.z + (double)wv.w * xv.w;
            }
            acc += __shfl_xor(acc, 1);  acc += __shfl_xor(acc, 2);
            acc += __shfl_xor(acc, 4);  acc += __shfl_xor(acc, 8);
            acc += __shfl_xor(acc, 16);
            if (sub == 0) cexact[c] = (float)(acc > 0.0 ? acc : 0.0);
        }
    }
    __syncthreads();

    // choose top (32-nd) of the band by exact value
    if (C > 32 && tid < C && cflag[tid] == 1) {
        int kq = TOPK - nd;
        float ex = cexact[tid]; int rankA = 0;
        for (int j = 0; j < na; ++j) {
            int cj = alist[j];
            float ej = cexact[cj]; int ij = (int)(((unsigned)cand[cj]) & 0xffffu);
            rankA += (ej > ex) || (ej == ex && ij < myidx);
        }
        if (rankA < kq) { cflag[tid] = 3; cvfin[tid] = ex; }
    }
    __syncthreads();

    // deterministic slot routing among the chosen
    if (tid < C && cflag[tid] >= 2) {
        float mv = cvfin[tid]; int rank = 0;
        for (int j = 0; j < C; ++j) {
            if (cflag[j] >= 2) {
                float vj = cvfin[j]; int ij = (int)(((unsigned)cand[j]) & 0xffffu);
                rank += (vj > mv) || (vj == mv && ij < myidx);
            }
        }
        if (rank < TOPK) { sval[rank] = mv; sidx[rank] = myidx; }
    }
    __syncthreads();

    // sparse decode from bf16 wdec + b_dec; nt store
    for (int d = tid; d < D_VIT; d += 256) {
        float o = bdec[d];
#pragma unroll
        for (int j = 0; j < TOPK; j++)
            o = fmaf(sval[j], __bfloat162float(wdecb[(size_t)sidx[j] * D_VIT + d]), o);
        __builtin_nontemporal_store(o, out + (size_t)row * D_VIT + d);
    }
}

extern "C" void kernel_launch(void* const* d_in, const int* in_sizes, int n_in,
                              void* d_out, int out_size, void* d_ws, size_t ws_size,
                              hipStream_t stream) {
    const float* x    = (const float*)d_in[0];
    const float* wenc = (const float*)d_in[1];
    const float* wdec = (const float*)d_in[2];
    const float* bdec = (const float*)d_in[3];
    float* out = (float*)d_out;
    int M = in_sizes[0] / D_VIT;

    size_t wt_b    = (size_t)D_SAE * D_VIT * sizeof(float);
    size_t wtb_b   = (size_t)D_SAE * D_VIT * sizeof(__hip_bfloat16);
    size_t xb_b    = (size_t)M * D_VIT * sizeof(__hip_bfloat16);
    size_t wdecb_b = (size_t)D_SAE * D_VIT * sizeof(__hip_bfloat16);
    size_t fixed   = wt_b + wtb_b + xb_b + wdecb_b;
    size_t row_b   = (size_t)D_SAE * sizeof(__hip_bfloat16) + NT64 * sizeof(__hip_bfloat16);

    float* wt             = (float*)d_ws;
    __hip_bfloat16* wtb   = (__hip_bfloat16*)((char*)d_ws + wt_b);
    __hip_bfloat16* xb    = (__hip_bfloat16*)((char*)d_ws + wt_b + wtb_b);
    __hip_bfloat16* wdecb = (__hip_bfloat16*)((char*)d_ws + wt_b + wtb_b + xb_b);

    long long chl = (long long)((ws_size > fixed ? ws_size - fixed : row_b) / row_b);
    int CH = (int)(chl < 1 ? 1 : (chl > (long long)M ? M : chl));
    if (CH > CHMAX) CH = CHMAX;
    if (CH >= 256 && CH < M) CH &= ~255;

    __hip_bfloat16* mx_buf = (__hip_bfloat16*)((char*)d_ws + fixed);
    __hip_bfloat16* actb   = (__hip_bfloat16*)((char*)d_ws + fixed
                                               + (size_t)CH * NT64 * sizeof(__hip_bfloat16));

    {
        dim3 g(D_SAE / 32, D_VIT / 32), b(32, 8);
        hipLaunchKernelGGL(k_transpose, g, b, 0, stream, wenc, wt, wtb);
    }
    {
        long long n = (long long)M * D_VIT;
        int blocks = (int)((n / 8 + 255) / 256);
        hipLaunchKernelGGL(k_cvt_x, dim3(blocks), dim3(256), 0, stream, x, bdec, xb, n);
    }
    {
        long long n = (long long)D_SAE * D_VIT;
        int blocks = (int)((n / 8 + 255) / 256);
        hipLaunchKernelGGL(k_cvt_w, dim3(blocks), dim3(256), 0, stream, wdec, wdecb, n);
    }
    for (int s = 0; s < M; s += CH) {
        int mr = (M - s) < CH ? (M - s) : CH;
        dim3 ge(D_SAE / GBN, (mr + GBM - 1) / GBM), be(512);
        hipLaunchKernelGGL(k_enc8, ge, be, 0, stream, xb, wtb, actb, mx_buf, s, mr, M);
        hipLaunchKernelGGL(k_select, dim3(mr), dim3(256), 0, stream,
                           actb, (const unsigned short*)mx_buf, x, bdec, wt, wdecb,
                           out, s, mr);
    }
}